// Round 6
// baseline (3044.923 us; speedup 1.0000x reference)
//
#include <hip/hip_runtime.h>
#include <math.h>

#define BB 4
#define TT 10
#define HH 96
#define WW 96
#define HWSZ 9216
#define PW 100
#define PSZ 10000
#define LL 5

typedef _Float16 half8 __attribute__((ext_vector_type(8)));
typedef _Float16 half4 __attribute__((ext_vector_type(4)));
typedef float floatx4 __attribute__((ext_vector_type(4)));

// ---------------- prep: weights -> f16, MFMA-friendly [co][k] layouts ----------------
// wi16/wh16: [co=32][k=1600], k = tap*64 + ci   (tap = ky*5+kx)
// wA16:      [co=192][k=576], k = tap*64 + ci   (tap = ky*3+kx)
// rw16:      [co=192][k=320], k = l*64 + c
// fw16:      [co=16(10 live)][k=800], k = tap*32 + ci
__global__ __launch_bounds__(256) void prep_weights(const float* __restrict__ i2f_w,
                                                    const float* __restrict__ h2f_w,
                                                    const float* __restrict__ i2h_w,
                                                    const float* __restrict__ ret_w,
                                                    const float* __restrict__ flows_w,
                                                    _Float16* __restrict__ wi16,
                                                    _Float16* __restrict__ wh16,
                                                    _Float16* __restrict__ wA16,
                                                    _Float16* __restrict__ rw16,
                                                    _Float16* __restrict__ fw16) {
    const int id = blockIdx.x * 256 + threadIdx.x;   // 0..287231
    if (id < 51200) {
        const int co = id / 1600, k = id % 1600, tap = k >> 6, ci = k & 63;
        wi16[id] = (_Float16)i2f_w[(co * 64 + ci) * 25 + tap];
    } else if (id < 102400) {
        const int r = id - 51200;
        const int co = r / 1600, k = r % 1600, tap = k >> 6, ci = k & 63;
        wh16[r] = (_Float16)h2f_w[(co * 64 + ci) * 25 + tap];
    } else if (id < 212992) {
        const int r = id - 102400;
        const int co = r / 576, k = r % 576, tap = k >> 6, ci = k & 63;
        wA16[r] = (_Float16)i2h_w[(co * 64 + ci) * 9 + tap];
    } else if (id < 274432) {
        const int r = id - 212992;
        rw16[r] = (_Float16)ret_w[r];   // already [co][320] with k = l*64+c
    } else {
        const int r = id - 274432;      // 0..12799
        const int co = r / 800, k = r % 800, tap = k >> 5, ci = k & 31;
        fw16[r] = (co < 10) ? (_Float16)flows_w[(co * 32 + ci) * 25 + tap] : (_Float16)0.0f;
    }
}

// ---------------- prep: x -> zero-padded f16 channel-last x16p[img][ppos][64] ---------
// ppos on a 100x100 grid, 2-px halo of zeros; interior (py,px) in [2,98)
__global__ __launch_bounds__(256) void prep_x16pad(const float* __restrict__ x,
                                                   _Float16* __restrict__ xp) {
    const int id = blockIdx.x * 256 + threadIdx.x;   // img*10000 + ppos
    if (id >= 40 * PSZ) return;
    const int img = id / PSZ, ppos = id % PSZ;
    const int py = ppos / PW, px = ppos % PW;
    _Float16* dst = xp + ((size_t)img * PSZ + ppos) * 64;
    if (py >= 2 && py < 98 && px >= 2 && px < 98) {
        const float* src = x + (size_t)img * 64 * HWSZ + (py - 2) * WW + (px - 2);
        #pragma unroll
        for (int i = 0; i < 8; i++) {
            half8 v;
            #pragma unroll
            for (int j = 0; j < 8; j++)
                v[j] = (_Float16)src[(size_t)(i * 8 + j) * HWSZ];
            *(half8*)(dst + i * 8) = v;
        }
    } else {
        const half8 z = {};
        #pragma unroll
        for (int i = 0; i < 8; i++) *(half8*)(dst + i * 8) = z;
    }
}

// ---------------- i2h: 3x3 conv as MFMA implicit GEMM, branch-free padded loads ------
// image remap: step t, batch b reads flat image q = t*4 + b
__global__ __launch_bounds__(256) void i2h_mfma(const _Float16* __restrict__ xp,
                                                const _Float16* __restrict__ wA16,
                                                const float* __restrict__ bias,
                                                _Float16* __restrict__ i2h16, int t) {
    const int wv = threadIdx.x >> 6;
    const int ln = threadIdx.x & 63;
    const int lm = ln & 15, q = ln >> 4;
    const int nt = blockIdx.x * 4 + wv;          // 0..2303
    const int b  = nt / 576;
    const int ti = nt % 576;
    const int y  = ti / 6;
    const int x0 = (ti % 6) * 16;
    const _Float16* xb = xp + (size_t)(t * BB + b) * PSZ * 64;

    floatx4 acc[12];
    #pragma unroll
    for (int mt = 0; mt < 12; mt++)
        #pragma unroll
        for (int r = 0; r < 4; r++)
            acc[mt][r] = bias[mt * 16 + q * 4 + r];

    for (int s = 0; s < 18; s++) {
        const int tap = s >> 1;
        const int ky = tap / 3 - 1, kx = tap % 3 - 1;
        const int ci0 = (s & 1) * 32;
        const int k0 = tap * 64 + ci0;
        const int ppos = (y + ky + 2) * PW + x0 + lm + kx + 2;
        const half8 bf = *(const half8*)(xb + (size_t)ppos * 64 + ci0 + q * 8);
        #pragma unroll
        for (int mt = 0; mt < 12; mt++) {
            const half8 af = *(const half8*)(wA16 + (size_t)(mt * 16 + lm) * 576 + k0 + q * 8);
            acc[mt] = __builtin_amdgcn_mfma_f32_16x16x32_f16(af, bf, acc[mt], 0, 0, 0);
        }
    }
    const int pos = y * WW + x0 + lm;
    _Float16* op = i2h16 + ((size_t)b * HWSZ + pos) * 192;
    #pragma unroll
    for (int mt = 0; mt < 12; mt++) {
        half4 pk;
        #pragma unroll
        for (int r = 0; r < 4; r++) pk[r] = (_Float16)acc[mt][r];
        *(half4*)(op + mt * 16 + q * 4) = pk;
    }
}

// ---------------- f1: tanh(conv5x5(x_t)+conv5x5(h)), merged phases, padded loads ------
__global__ __launch_bounds__(256) void f1_mfma(const _Float16* __restrict__ xp,
                                               const _Float16* __restrict__ hp16,
                                               const _Float16* __restrict__ wi16,
                                               const _Float16* __restrict__ wh16,
                                               const float* __restrict__ bi,
                                               const float* __restrict__ bh,
                                               _Float16* __restrict__ f116, int t) {
    const int wv = threadIdx.x >> 6;
    const int ln = threadIdx.x & 63;
    const int lm = ln & 15, q = ln >> 4;
    const int nt = blockIdx.x * 4 + wv;          // 0..2303
    const int b  = nt / 576;
    const int ti = nt % 576;
    const int y  = ti / 6, xx = (ti % 6) * 16;

    floatx4 accx[2], acch[2];
    #pragma unroll
    for (int mt = 0; mt < 2; mt++)
        #pragma unroll
        for (int r = 0; r < 4; r++) {
            accx[mt][r] = bi[mt * 16 + q * 4 + r] + bh[mt * 16 + q * 4 + r];
            acch[mt][r] = 0.0f;
        }

    const _Float16* sx = xp + (size_t)(b * TT + t) * PSZ * 64;  // x_t = inputs[:, t]
    const _Float16* sh = hp16 + (size_t)b * PSZ * 64;

    for (int s = 0; s < 50; s++) {
        const int tap = s >> 1;
        const int ky = tap / 5 - 2, kx = tap % 5 - 2;
        const int ci0 = (s & 1) * 32;
        const int k0 = tap * 64 + ci0;
        const size_t off = (size_t)((y + ky + 2) * PW + xx + lm + kx + 2) * 64 + ci0 + q * 8;
        const half8 bx = *(const half8*)(sx + off);
        const half8 bh8 = *(const half8*)(sh + off);
        const half8 ax0 = *(const half8*)(wi16 + (size_t)(0 * 16 + lm) * 1600 + k0 + q * 8);
        const half8 ax1 = *(const half8*)(wi16 + (size_t)(1 * 16 + lm) * 1600 + k0 + q * 8);
        const half8 ah0 = *(const half8*)(wh16 + (size_t)(0 * 16 + lm) * 1600 + k0 + q * 8);
        const half8 ah1 = *(const half8*)(wh16 + (size_t)(1 * 16 + lm) * 1600 + k0 + q * 8);
        accx[0] = __builtin_amdgcn_mfma_f32_16x16x32_f16(ax0, bx,  accx[0], 0, 0, 0);
        accx[1] = __builtin_amdgcn_mfma_f32_16x16x32_f16(ax1, bx,  accx[1], 0, 0, 0);
        acch[0] = __builtin_amdgcn_mfma_f32_16x16x32_f16(ah0, bh8, acch[0], 0, 0, 0);
        acch[1] = __builtin_amdgcn_mfma_f32_16x16x32_f16(ah1, bh8, acch[1], 0, 0, 0);
    }
    const int ppos = (y + 2) * PW + xx + lm + 2;
    _Float16* op = f116 + ((size_t)b * PSZ + ppos) * 32;
    #pragma unroll
    for (int mt = 0; mt < 2; mt++) {
        half4 pk;
        #pragma unroll
        for (int r = 0; r < 4; r++)
            pk[r] = (_Float16)tanhf(accx[mt][r] + acch[mt][r]);
        *(half4*)(op + mt * 16 + q * 4) = pk;
    }
}

// ---------------- flows: conv5x5(f1,32->10) as MFMA, padded branch-free loads ---------
__global__ __launch_bounds__(256) void flows_mfma(const _Float16* __restrict__ f116,
                                                  const _Float16* __restrict__ fw16,
                                                  const float* __restrict__ bias,
                                                  float* __restrict__ out) {
    const int wv = threadIdx.x >> 6;
    const int ln = threadIdx.x & 63;
    const int lm = ln & 15, q = ln >> 4;
    const int nt = blockIdx.x * 4 + wv;          // 0..2303
    const int b  = nt / 576;
    const int ti = nt % 576;
    const int y  = ti / 6, xx = (ti % 6) * 16;

    floatx4 acc;
    #pragma unroll
    for (int r = 0; r < 4; r++) {
        const int c = q * 4 + r;
        acc[r] = (c < 10) ? bias[c] : 0.0f;
    }
    const _Float16* fb = f116 + (size_t)b * PSZ * 32;
    for (int tap = 0; tap < 25; tap++) {
        const int ky = tap / 5 - 2, kx = tap % 5 - 2;
        const int ppos = (y + ky + 2) * PW + xx + lm + kx + 2;
        const half8 bf = *(const half8*)(fb + (size_t)ppos * 32 + q * 8);
        const half8 af = *(const half8*)(fw16 + (size_t)lm * 800 + tap * 32 + q * 8);
        acc = __builtin_amdgcn_mfma_f32_16x16x32_f16(af, bf, acc, 0, 0, 0);
    }
    const int pos = y * WW + xx + lm;
    #pragma unroll
    for (int r = 0; r < 4; r++) {
        const int c = q * 4 + r;
        if (c < 10)
            out[((size_t)b * 10 + c) * HWSZ + pos] = acc[r];
    }
}

// ---------------- warp: bilinear warp of padded h16 by -flow, f16 channel-last out ----
__global__ __launch_bounds__(256) void warp_kernel(const _Float16* __restrict__ hp16,
                                                   const float* __restrict__ flows,
                                                   _Float16* __restrict__ w16) {
    const int p = blockIdx.x * 256 + threadIdx.x;
    const int l = blockIdx.y;
    const int b = blockIdx.z;
    const int y = p / WW, xx = p % WW;
    const float f0  = -flows[((size_t)b * 10 + l * 2 + 0) * HWSZ + p];
    const float f1v = -flows[((size_t)b * 10 + l * 2 + 1) * HWSZ + p];
    const float nx = 2.0f * ((float)xx + f0)  / (float)(WW - 1) - 1.0f;
    const float ny = 2.0f * ((float)y  + f1v) / (float)(HH - 1) - 1.0f;
    const float fx = (nx + 1.0f) * (WW * 0.5f) - 0.5f;
    const float fy = (ny + 1.0f) * (HH * 0.5f) - 0.5f;
    const float x0f = floorf(fx), y0f = floorf(fy);
    const float wx = fx - x0f, wy = fy - y0f;
    const int x0 = (int)x0f, y0 = (int)y0f;

    int   off[4];
    float wgt[4];
    #pragma unroll
    for (int k = 0; k < 4; k++) {
        const int yi = y0 + (k >> 1);
        const int xi = x0 + (k & 1);
        const bool ok = (xi >= 0 && xi < WW && yi >= 0 && yi < HH);
        const int yc = min(max(yi, 0), HH - 1);
        const int xc = min(max(xi, 0), WW - 1);
        off[k] = (yc + 2) * PW + xc + 2;             // padded-grid offset
        const float wk = ((k & 1) ? wx : 1.0f - wx) * ((k >> 1) ? wy : 1.0f - wy);
        wgt[k] = ok ? wk : 0.0f;
    }
    const _Float16* hb = hp16 + (size_t)b * PSZ * 64;
    _Float16* dst = w16 + ((size_t)b * HWSZ + p) * 320 + l * 64;
    #pragma unroll
    for (int i = 0; i < 8; i++) {
        const half8 v0 = *(const half8*)(hb + (size_t)off[0] * 64 + i * 8);
        const half8 v1 = *(const half8*)(hb + (size_t)off[1] * 64 + i * 8);
        const half8 v2 = *(const half8*)(hb + (size_t)off[2] * 64 + i * 8);
        const half8 v3 = *(const half8*)(hb + (size_t)off[3] * 64 + i * 8);
        half8 o;
        #pragma unroll
        for (int j = 0; j < 8; j++)
            o[j] = (_Float16)((float)v0[j] * wgt[0] + (float)v1[j] * wgt[1]
                            + (float)v2[j] * wgt[2] + (float)v3[j] * wgt[3]);
        *(half8*)(dst + i * 8) = o;
    }
}

// ---------------- h2h (1x1, 320->192) as MFMA + fused GRU gates -----------------------
__global__ __launch_bounds__(256) void gate_mfma(const _Float16* __restrict__ w16,
                                                 const _Float16* __restrict__ rw16,
                                                 const float* __restrict__ ret_b,
                                                 const _Float16* __restrict__ i2h16,
                                                 float* __restrict__ h,
                                                 _Float16* __restrict__ hp16,
                                                 float* __restrict__ outs,
                                                 float* __restrict__ last_h, int t) {
    const int wv = threadIdx.x >> 6;
    const int ln = threadIdx.x & 63;
    const int lm = ln & 15, q = ln >> 4;
    const int nt = blockIdx.x * 4 + wv;          // 0..2303
    const int b  = nt / 576;
    const int ti = nt % 576;
    const int pos = ti * 16 + lm;

    floatx4 acc[12];
    #pragma unroll
    for (int mt = 0; mt < 12; mt++)
        #pragma unroll
        for (int r = 0; r < 4; r++)
            acc[mt][r] = ret_b[mt * 16 + q * 4 + r];

    const _Float16* wb = w16 + ((size_t)b * HWSZ + pos) * 320;
    for (int s = 0; s < 10; s++) {
        const int k0 = s * 32;
        const half8 bf = *(const half8*)(wb + k0 + q * 8);
        #pragma unroll
        for (int mt = 0; mt < 12; mt++) {
            const half8 af = *(const half8*)(rw16 + (size_t)(mt * 16 + lm) * 320 + k0 + q * 8);
            acc[mt] = __builtin_amdgcn_mfma_f32_16x16x32_f16(af, bf, acc[mt], 0, 0, 0);
        }
    }

    const int ppos = (ti / 6 + 2) * PW + (ti % 6) * 16 + lm + 2;
    const _Float16* ip = i2h16 + ((size_t)b * HWSZ + pos) * 192;
    #pragma unroll
    for (int mt = 0; mt < 4; mt++) {
        const half4 vr = *(const half4*)(ip + mt * 16 + q * 4);
        const half4 vu = *(const half4*)(ip + 64 + mt * 16 + q * 4);
        const half4 vm = *(const half4*)(ip + 128 + mt * 16 + q * 4);
        half4 pk;
        #pragma unroll
        for (int r = 0; r < 4; r++) {
            const int c = mt * 16 + q * 4 + r;
            const float gr = acc[mt][r], gu = acc[mt + 4][r], gm = acc[mt + 8][r];
            const float rg = 1.0f / (1.0f + expf(-((float)vr[r] + gr)));
            const float ug = 1.0f / (1.0f + expf(-((float)vu[r] + gu)));
            const float mg = tanhf((float)vm[r] + rg * gm);
            const size_t hi = ((size_t)b * 64 + c) * HWSZ + pos;
            const float nh = ug * h[hi] + (1.0f - ug) * mg;
            h[hi] = nh;
            outs[(((size_t)b * TT + t) * 64 + c) * HWSZ + pos] = nh;
            if (t == TT - 1) last_h[hi] = nh;
            pk[r] = (_Float16)nh;
        }
        *(half4*)(hp16 + ((size_t)b * PSZ + ppos) * 64 + mt * 16 + q * 4) = pk;
    }
}

extern "C" void kernel_launch(void* const* d_in, const int* in_sizes, int n_in,
                              void* d_out, int out_size, void* d_ws, size_t ws_size,
                              hipStream_t stream) {
    const float* inputs  = (const float*)d_in[0];
    const float* i2h_w   = (const float*)d_in[1];
    const float* i2h_b   = (const float*)d_in[2];
    const float* i2f_w   = (const float*)d_in[3];
    const float* i2f_b   = (const float*)d_in[4];
    const float* h2f_w   = (const float*)d_in[5];
    const float* h2f_b   = (const float*)d_in[6];
    const float* flows_w = (const float*)d_in[7];
    const float* flows_b = (const float*)d_in[8];
    const float* ret_w   = (const float*)d_in[9];
    const float* ret_b   = (const float*)d_in[10];

    float* out = (float*)d_out;

    // workspace layout (bytes), total ~108.3 MB
    char* base = (char*)d_ws;
    float*    h        = (float*)base;      base += 9437184;    // 4*64*9216 f32
    _Float16* i2h16    = (_Float16*)base;   base += 14155776;   // 4*9216*192 f16
    float*    flowsb   = (float*)base;      base += 1474560;    // 4*10*9216 f32
    _Float16* warped16 = (_Float16*)base;   base += 23592960;   // 4*9216*320 f16
    _Float16* f116p    = (_Float16*)base;   base += 2560000;    // 4*10000*32 f16 (padded)
    _Float16* x16p     = (_Float16*)base;   base += 51200000;   // 40*10000*64 f16 (padded)
    _Float16* h16p     = (_Float16*)base;   base += 5120000;    // 4*10000*64 f16 (padded)
    _Float16* wi16     = (_Float16*)base;   base += 102400;     // 32*1600
    _Float16* wh16     = (_Float16*)base;   base += 102400;
    _Float16* wA16     = (_Float16*)base;   base += 221184;     // 192*576
    _Float16* rw16     = (_Float16*)base;   base += 122880;     // 192*320
    _Float16* fw16     = (_Float16*)base;   base += 25600;      // 16*800

    float* outs   = out;
    float* last_h = out + (size_t)BB * TT * 64 * HWSZ;

    hipMemsetAsync(h,     0, 9437184, stream);   // h0 = 0
    hipMemsetAsync(h16p,  0, 5120000, stream);   // h0 = 0 + permanent halo zeros
    hipMemsetAsync(f116p, 0, 2560000, stream);   // halo zeros (interior overwritten each t)

    prep_weights<<<1122, 256, 0, stream>>>(i2f_w, h2f_w, i2h_w, ret_w, flows_w,
                                           wi16, wh16, wA16, rw16, fw16);
    prep_x16pad<<<1563, 256, 0, stream>>>(inputs, x16p);

    for (int t = 0; t < TT; t++) {
        i2h_mfma<<<576, 256, 0, stream>>>(x16p, wA16, i2h_b, i2h16, t);
        f1_mfma<<<576, 256, 0, stream>>>(x16p, h16p, wi16, wh16, i2f_b, h2f_b, f116p, t);
        flows_mfma<<<576, 256, 0, stream>>>(f116p, fw16, flows_b, flowsb);
        warp_kernel<<<dim3(36, LL, BB), 256, 0, stream>>>(h16p, flowsb, warped16);
        gate_mfma<<<576, 256, 0, stream>>>(warped16, rw16, ret_b, i2h16, h, h16p, outs, last_h, t);
    }
}